// Round 19
// baseline (123.348 us; speedup 1.0000x reference)
//
#include <hip/hip_runtime.h>
#include <hip/hip_bf16.h>
#include <cstddef>

#define B_   2
#define S_   2048
#define HID_ 1152
#define NH_  16
#define NKV_ 4
#define HD_  72
#define MTOT (B_ * S_)   // 4096
#define KVDIM (NKV_ * HD_)  // 288

typedef float f32x4 __attribute__((ext_vector_type(4)));
typedef float f32x16 __attribute__((ext_vector_type(16)));
typedef short bf16x8 __attribute__((ext_vector_type(8)));
typedef short s4v __attribute__((ext_vector_type(4)));

__device__ __forceinline__ float bf2f(short x) {
  unsigned int u = ((unsigned int)(unsigned short)x) << 16;
  return __builtin_bit_cast(float, u);
}
__device__ __forceinline__ short f2bf(float f) {
  unsigned int u = __builtin_bit_cast(unsigned int, f);
  u += 0x7fff + ((u >> 16) & 1);   // RNE
  return (short)(u >> 16);
}

// hardware v_exp_f32 (2^x) — exp2f() without -ffast-math lowers to ~25 VALU ops.
__device__ __forceinline__ float fast_exp2(float x) {
#if __has_builtin(__builtin_amdgcn_exp2f)
  return __builtin_amdgcn_exp2f(x);
#else
  return exp2f(x);
#endif
}

__device__ __forceinline__ void async16(const short* g, short* lds) {
  __builtin_amdgcn_global_load_lds((const __attribute__((address_space(1))) void*)g,
                                   (__attribute__((address_space(3))) void*)lds,
                                   16, 0, 0);
}

// ------- fused fp32->bf16 convert + RoPE table + Vt ones-rows, 1 launch -------
__global__ void k_cvt_all(const float4* __restrict__ s0, const float4* __restrict__ s1,
                          const float4* __restrict__ s2, const float4* __restrict__ s3,
                          const float4* __restrict__ s4,
                          s4v* __restrict__ d0, s4v* __restrict__ d1, s4v* __restrict__ d2,
                          s4v* __restrict__ d3, s4v* __restrict__ d4,
                          float2* __restrict__ tab, short* __restrict__ Vt,
                          int n0, int n1, int n2, int n3, int n4t) {
  int ncvt = n0 + n1 + n2 + n3 + n4t;
  int ntab = S_ * 36;
  int total = ncvt + ntab + 32768;
  for (int i = blockIdx.x * blockDim.x + threadIdx.x; i < total;
       i += gridDim.x * blockDim.x) {
    if (i < ncvt) {
      const float4* s;
      s4v* d;
      int off = i;
      bool perm = false;
      if (off < n0) { s = s0; d = d0; }
      else {
        off -= n0;
        if (off < n1) { s = s1; d = d1; perm = true; }       // wq
        else {
          off -= n1;
          if (off < n2) { s = s2; d = d2; perm = true; }     // wk
          else {
            off -= n2;
            if (off < n3) { s = s3; d = d3; }
            else { off -= n3; s = s4; d = d4; }
          }
        }
      }
      float4 v = s[off];
      s4v o = { f2bf(v.x), f2bf(v.y), f2bf(v.z), f2bf(v.w) };
      int out = off;
      if (perm) {
        int r = off / 288, k4 = off - r * 288;   // 288 float4 per 1152-col row
        int hh = r / 72, ii = r - hh * 72;
        int pr = hh * 72 + (ii < 36 ? 2 * ii : 2 * (ii - 36) + 1);
        out = pr * 288 + k4;
      }
      d[out] = o;
    } else if (i < ncvt + ntab) {
      int idx = i - ncvt;
      int ii = idx % 36, s = idx / 36;
      float freq = powf(10000.0f, -(float)ii / 36.0f);
      float a = (float)s * freq;
      tab[idx] = make_float2(cosf(a), sinf(a));
    } else {
      int idx2 = i - ncvt - ntab;        // 0..32767, s4v units
      int t = idx2 << 2;
      int sp = t & 2047;
      int rest = t >> 11;                // 0..63
      int dr = rest & 7;                 // row - 72
      int bkv = rest >> 3;
      s4v val = {};
      if (dr == 0) { val[0] = (short)0x3F80; val[1] = (short)0x3F80;
                     val[2] = (short)0x3F80; val[3] = (short)0x3F80; }
      *(s4v*)(Vt + (size_t)bkv * 163840 + (size_t)(72 + dr) * 2048 + sp) = val;
    }
  }
}

// ---------------- GEMM geometry: 128x128x4-wave, LDS DOUBLE-BUFFERED --------
#define BM 128
#define BN 128
#define BK 32

// Fused QKV projection: C = X @ [wq;wk;wv]^T over N=1728, one launch.
__global__ __launch_bounds__(256) void k_gemm_qkv(const short* __restrict__ A,
                                                  const short* __restrict__ Wq,
                                                  const short* __restrict__ Wk,
                                                  const short* __restrict__ Wv,
                                                  short* __restrict__ Qo,
                                                  short* __restrict__ Ko,
                                                  short* __restrict__ Vt,
                                                  const float2* __restrict__ tab) {
  const int K = HID_, NTOT = 1728;
  __shared__ short smem[16384];           // 2x (As 4096 + Bs 4096) shorts
  short* As0 = smem;
  short* Bs0 = smem + 4096;
  short* As1 = smem + 8192;
  short* Bs1 = smem + 12288;
  const int tid = threadIdx.x;
  const int l = tid & 63;
  const int w = tid >> 6;
  const int bm = blockIdx.x * BM;
  const int bn = blockIdx.y * BN;
  const int wr = (w >> 1) * 64;
  const int wc = (w & 1) * 64;
  const int c15 = l & 15, g = l >> 4;
  const int r0 = tid >> 2;
  const int c0 = (tid & 3) * 8;

  const short* srcA[2];
  const short* srcB[2];
#pragma unroll
  for (int it = 0; it < 2; ++it) {
    int ar = bm + it * 64 + r0;
    int br = bn + it * 64 + r0;
    if (br > NTOT - 1) br = NTOT - 1;
    const short* bsrc;
    if (br < 1152)      bsrc = Wq + (size_t)br * K;
    else if (br < 1440) bsrc = Wk + (size_t)(br - 1152) * K;
    else                bsrc = Wv + (size_t)(br - 1440) * K;
    srcA[it] = A + (size_t)ar * K + c0;
    srcB[it] = bsrc + c0;
  }

  auto STAGE = [&](short* Ad, short* Bd) {
#pragma unroll
    for (int it = 0; it < 2; ++it) {
      async16(srcA[it], &Ad[(it * 64 + r0) * BK + c0]);
      async16(srcB[it], &Bd[(it * 64 + r0) * BK + c0]);
      srcA[it] += BK;
      srcB[it] += BK;
    }
  };

  f32x4 acc[4][4] = {};

  STAGE(As0, Bs0);
  short *Ac = As0, *Bc = Bs0, *An = As1, *Bn = Bs1;

  for (int k0 = 0; k0 < K; k0 += BK) {
    asm volatile("s_waitcnt vmcnt(0)" ::: "memory");
    __builtin_amdgcn_sched_barrier(0);
    __syncthreads();
    if (k0 + BK < K) STAGE(An, Bn);

    bf16x8 af[4], bfr[4];
#pragma unroll
    for (int t = 0; t < 4; ++t) {
      af[t]  = *(const bf16x8*)&Ac[(wr + t * 16 + c15) * BK + g * 8];
      bfr[t] = *(const bf16x8*)&Bc[(wc + t * 16 + c15) * BK + g * 8];
    }
#pragma unroll
    for (int mt = 0; mt < 4; ++mt)
#pragma unroll
      for (int nt = 0; nt < 4; ++nt)
        acc[mt][nt] = __builtin_amdgcn_mfma_f32_16x16x32_bf16(af[mt], bfr[nt], acc[mt][nt], 0, 0, 0);

    short* t1 = Ac; Ac = An; An = t1;
    short* t2 = Bc; Bc = Bn; Bn = t2;
  }

#pragma unroll
  for (int mt = 0; mt < 4; ++mt)
#pragma unroll
    for (int nt = 0; nt < 4; ++nt) {
      int col = bn + wc + nt * 16 + c15;       // range is wave-uniform per nt
      if (col < 1152) {
#pragma unroll
        for (int j = 0; j < 4; ++j) {
          int row = bm + wr + mt * 16 + g * 4 + j;
          Qo[(size_t)row * HID_ + col] = f2bf(acc[mt][nt][j]);
        }
      } else if (col < 1440) {
        int ch = col - 1152;
        int ii = (ch % 72) >> 1;               // pairs adjacent (permuted wk)
#pragma unroll
        for (int j = 0; j < 4; ++j) {
          int row = bm + wr + mt * 16 + g * 4 + j;
          float v = acc[mt][nt][j];
          float p = __shfl_xor(v, 1);
          float2 cs = tab[(size_t)(row & (S_ - 1)) * 36 + ii];
          float r = (c15 & 1) ? (v * cs.x + p * cs.y)
                              : (v * cs.x - p * cs.y);
          Ko[(size_t)row * KVDIM + ch] = f2bf(r);
        }
      } else if (col < NTOT) {
        int cv = col - 1440;
        int d = cv % 72, kvh = cv / 72;
        int row0 = bm + wr + mt * 16 + g * 4;
        int bkv = (row0 >> 11) * 4 + kvh;
        s4v out;
#pragma unroll
        for (int j = 0; j < 4; ++j) out[j] = f2bf(acc[mt][nt][j]);
        *(s4v*)(Vt + (size_t)bkv * 163840 + (size_t)d * 2048 + (row0 & 2047)) = out;
      }
    }
}

// Output projection: C[M,N] = A[M,K] * B[N,K]^T, fp32 out (double-buffered)
__global__ __launch_bounds__(256) void k_gemm_o(const short* __restrict__ A,
                                                const short* __restrict__ Bm,
                                                float* __restrict__ C,
                                                int M, int N, int K) {
  __shared__ short smem[16384];
  short* As0 = smem;
  short* Bs0 = smem + 4096;
  short* As1 = smem + 8192;
  short* Bs1 = smem + 12288;
  const int tid = threadIdx.x;
  const int l = tid & 63;
  const int w = tid >> 6;
  const int bm = blockIdx.x * BM;
  const int bn = blockIdx.y * BN;
  const int wr = (w >> 1) * 64;
  const int wc = (w & 1) * 64;
  const int c15 = l & 15, g = l >> 4;
  const int r0 = tid >> 2;
  const int c0 = (tid & 3) * 8;

  const short* srcA[2];
  const short* srcB[2];
#pragma unroll
  for (int it = 0; it < 2; ++it) {
    int ar = bm + it * 64 + r0;
    int br = bn + it * 64 + r0;
    if (br > N - 1) br = N - 1;
    srcA[it] = A + (size_t)ar * K + c0;
    srcB[it] = Bm + (size_t)br * K + c0;
  }

  auto STAGE = [&](short* Ad, short* Bd) {
#pragma unroll
    for (int it = 0; it < 2; ++it) {
      async16(srcA[it], &Ad[(it * 64 + r0) * BK + c0]);
      async16(srcB[it], &Bd[(it * 64 + r0) * BK + c0]);
      srcA[it] += BK;
      srcB[it] += BK;
    }
  };

  f32x4 acc[4][4] = {};

  STAGE(As0, Bs0);
  short *Ac = As0, *Bc = Bs0, *An = As1, *Bn = Bs1;

  for (int k0 = 0; k0 < K; k0 += BK) {
    asm volatile("s_waitcnt vmcnt(0)" ::: "memory");
    __builtin_amdgcn_sched_barrier(0);
    __syncthreads();
    if (k0 + BK < K) STAGE(An, Bn);

    bf16x8 af[4], bfr[4];
#pragma unroll
    for (int t = 0; t < 4; ++t) {
      af[t]  = *(const bf16x8*)&Ac[(t * 16 + c15 + wr) * BK + g * 8];
      bfr[t] = *(const bf16x8*)&Bc[(wc + t * 16 + c15) * BK + g * 8];
    }
#pragma unroll
    for (int mt = 0; mt < 4; ++mt)
#pragma unroll
      for (int nt = 0; nt < 4; ++nt)
        acc[mt][nt] = __builtin_amdgcn_mfma_f32_16x16x32_bf16(af[mt], bfr[nt], acc[mt][nt], 0, 0, 0);

    short* t1 = Ac; Ac = An; An = t1;
    short* t2 = Bc; Bc = Bn; Bn = t2;
  }

#pragma unroll
  for (int mt = 0; mt < 4; ++mt)
#pragma unroll
    for (int nt = 0; nt < 4; ++nt)
#pragma unroll
      for (int j = 0; j < 4; ++j) {
        int row = bm + wr + mt * 16 + g * 4 + j;
        int col = bn + wc + nt * 16 + c15;
        if (col < N) C[(size_t)row * N + col] = acc[mt][nt][j];
      }
}

// ---------------- Flash attention: 32x32 MFMA (2x FLOP per LDS byte) --------
// 512 thr = 2 kt-split groups x 4 heads; each wave owns 32 q-rows. Per group:
// double-buffered Ks[64 kcol][80 d] (d 72..79 garbage x Q-zeros) + Vs[73][64]
// (8-slot XOR swizzle; row 72 = ones for the free denominator; dt=2 reads
// clamp d->72). KT=64. P transposed through dead Ksc per 32-col phase; PV of
// phase A interleaved before phase-B write to hide fence latency. Fixed-shift
// softmax (2^(s-8), hw exp); split-K halves combined through LDS at the end.
#define QB 32
#define KT 64

__global__ __launch_bounds__(512, 2) void k_flash(const short* __restrict__ Q,
                                                  const short* __restrict__ Kg,
                                                  const short* __restrict__ Vt,
                                                  short* __restrict__ O,
                                                  const float2* __restrict__ tab) {
  const int bid = blockIdx.x;
  const int bkv = bid & 7;            // one (b,kv) per XCD -> K/V L2-resident
  const int sidx = bid >> 3;
  const int qt = (bid < 256) ? sidx : 95 - sidx;   // paired so CU sums ~const
  const int b = bkv >> 2, kv = bkv & 3;
  const int tid = threadIdx.x;
  const int w = tid >> 6, l = tid & 63;
  const int grp = w >> 2, hw = w & 3;
  const int gtid = tid & 255;
  const int h = kv * 4 + hw;
  const int q0 = qt * QB;
  const int c31 = l & 31, h5 = l >> 5;

  // 78336 B -> 2 blocks/CU, 16 waves/CU. Per group: (Ks 5120 + Vs 4672) x2.
  __shared__ short lds[39168];
  short* gb = lds + grp * 19584;
  short* Ks0 = gb;
  short* Vs0 = gb + 5120;
  short* Ks1 = gb + 9792;
  short* Vs1 = gb + 14912;

  const float SCL = 0.117851130f * 1.4426950408889634f;  // 1/sqrt(72)*log2(e)
  const float SHIFT = 8.0f;

  const short* Qbase = Q + (size_t)(b * S_) * HID_ + h * HD_;
  const short* Kbase = Kg + (size_t)(b * S_) * KVDIM + kv * HD_;
  const short* Vbase = Vt + (size_t)bkv * 80 * S_;

  // lane offsets
  const int lane_k = c31 * 80 + h5 * 8;        // + ct*2560 + ks*16
  int vbase[3], ve7[3];
#pragma unroll
  for (int dt = 0; dt < 3; ++dt) {
    int rowd = dt * 32 + c31;
    if (rowd > 72) rowd = 72;                  // clamp into ones row
    vbase[dt] = rowd * 64;
    ve7[dt] = rowd & 7;
  }
  const int rbase = q0 + 4 * h5;               // + (r&3) + 8*(r>>2)

  // Q fragments: load + in-register RoPE (pairs adjacent) + pre-scale
  bf16x8 qf[5];
  const bf16x8 zfrag = {0, 0, 0, 0, 0, 0, 0, 0};
  {
    int row = q0 + c31;
    const short* qrow = Qbase + (size_t)row * HID_;
    const float2* trow = tab + (size_t)row * 36;
#pragma unroll
    for (int ks = 0; ks < 5; ++ks) {
      int d0 = ks * 16 + h5 * 8;
      if (d0 < HD_) {
        bf16x8 raw = *(const bf16x8*)(qrow + d0);
        bf16x8 o;
#pragma unroll
        for (int e = 0; e < 8; e += 2) {
          float2 cs = trow[(d0 + e) >> 1];
          float x1 = bf2f(raw[e]), x2 = bf2f(raw[e + 1]);
          o[e]     = f2bf((x1 * cs.x - x2 * cs.y) * SCL);
          o[e + 1] = f2bf((x2 * cs.x + x1 * cs.y) * SCL);
        }
        qf[ks] = o;
      } else {
        qf[ks] = zfrag;
      }
    }
  }

  f32x16 accO[3] = {};

  const int nkt_t = (qt + 2) >> 1;           // total K-tiles for this q-tile
  const int steps = (nkt_t + 1) >> 1;
  const int kt_lo = grp ? steps : 0;
  const int kt_hi = grp ? nkt_t : steps;
  const int nfull = (32 * qt + 1) >> 6;      // fully-unmasked tiles

  // staging descriptors: K = 640 chunks (row/10), V = 584 chunks (73x8 slots)
  int soff[5], doff[5], knd[5];
#pragma unroll
  for (int i = 0; i < 5; ++i) {
    int c = gtid + 256 * i;
    if (c < 640) {
      int r = c / 10, cc = c - r * 10;
      soff[i] = r * KVDIM + cc * 8;
      doff[i] = c * 8;
      knd[i] = 0;
    } else if (c < 1224) {
      int c2 = c - 640;
      int r = c2 >> 3, sl = c2 & 7;
      soff[i] = r * S_ + ((sl ^ (r & 7)) << 3);
      doff[i] = c2 * 8;
      knd[i] = 1;
    } else {
      knd[i] = 2;
    }
  }
  const short* kpS = Kbase + (size_t)kt_lo * KT * KVDIM;
  const short* vpS = Vbase + kt_lo * KT;

  auto STAGE = [&](short* Kd, short* Vd) {
#pragma unroll
    for (int i = 0; i < 5; ++i) {
      if (knd[i] == 0)      async16(kpS + soff[i], Kd + doff[i]);
      else if (knd[i] == 1) async16(vpS + soff[i], Vd + doff[i]);
    }
    kpS += KT * KVDIM;
    vpS += KT;
  };

  if (kt_lo < kt_hi) STAGE(Ks0, Vs0);
  short *Ksc = Ks0, *Vsc = Vs0, *Ksn = Ks1, *Vsn = Vs1;

  for (int s = 0; s < steps; ++s) {
    const int kt = kt_lo + s;
    const bool act = kt < kt_hi;
    asm volatile("s_waitcnt vmcnt(0)" ::: "memory");
    __builtin_amdgcn_sched_barrier(0);
    __syncthreads();
    if (act && kt + 1 < kt_hi) STAGE(Ksn, Vsn);

    f32x16 sc0 = {}, sc1 = {};
    if (act) {
      const int kbase = kt * KT;
      // ---- QK^T: 2 ct-tiles x 5 ks ----
      __builtin_amdgcn_s_setprio(1);
#pragma unroll
      for (int ks = 0; ks < 5; ++ks) {
        bf16x8 kf0 = *(const bf16x8*)&Ksc[lane_k + ks * 16];
        bf16x8 kf1 = *(const bf16x8*)&Ksc[lane_k + 2560 + ks * 16];
        sc0 = __builtin_amdgcn_mfma_f32_32x32x16_bf16(qf[ks], kf0, sc0, 0, 0, 0);
        sc1 = __builtin_amdgcn_mfma_f32_32x32x16_bf16(qf[ks], kf1, sc1, 0, 0, 0);
      }
      __builtin_amdgcn_s_setprio(0);

      // ---- mask + fixed-shift exp2 ----
      if (kt >= nfull) {
        int col0 = kbase + c31;
#pragma unroll
        for (int r = 0; r < 16; ++r) {
          int row = rbase + (r & 3) + 8 * (r >> 2);
          if (col0 > row)      sc0[r] = -1e30f;
          if (col0 + 32 > row) sc1[r] = -1e30f;
        }
      }
#pragma unroll
      for (int r = 0; r < 16; ++r) {
        sc0[r] = fast_exp2(sc0[r] - SHIFT);
        sc1[r] = fast_exp2(sc1[r] - SHIFT);
      }
    }

    // all group waves done reading Ksc -> safe to overwrite with P
    __syncthreads();
    if (act) {
      short* Pw = Ksc + hw * 1152;
      const int pwb = 4 * h5 * 36 + c31;
      const int prb = c31 * 36 + h5 * 8;
      // phase A: P cols 0..31
#pragma unroll
      for (int r = 0; r < 16; ++r)
        Pw[pwb + ((r & 3) + 8 * (r >> 2)) * 36] = f2bf(sc0[r]);
      asm volatile("s_waitcnt lgkmcnt(0)" ::: "memory");
      __builtin_amdgcn_sched_barrier(0);
      bf16x8 pa0 = *(const bf16x8*)&Pw[prb];
      bf16x8 pa1 = *(const bf16x8*)&Pw[prb + 16];
      asm volatile("s_waitcnt lgkmcnt(0)" ::: "memory");
      __builtin_amdgcn_sched_barrier(0);
      // PV phase A (hides phase-B write latency under MFMA)
      __builtin_amdgcn_s_setprio(1);
#pragma unroll
      for (int dt = 0; dt < 3; ++dt) {
        bf16x8 vb0 = *(const bf16x8*)&Vsc[vbase[dt] + ((h5 ^ ve7[dt]) << 3)];
        bf16x8 vb1 = *(const bf16x8*)&Vsc[vbase[dt] + (((2 + h5) ^ ve7[dt]) << 3)];
        accO[dt] = __builtin_amdgcn_mfma_f32_32x32x16_bf16(pa0, vb0, accO[dt], 0, 0, 0);
        accO[dt] = __builtin_amdgcn_mfma_f32_32x32x16_bf16(pa1, vb1, accO[dt], 0, 0, 0);
      }
      __builtin_amdgcn_s_setprio(0);
      // phase B: P cols 32..63
#pragma unroll
      for (int r = 0; r < 16; ++r)
        Pw[pwb + ((r & 3) + 8 * (r >> 2)) * 36] = f2bf(sc1[r]);
      asm volatile("s_waitcnt lgkmcnt(0)" ::: "memory");
      __builtin_amdgcn_sched_barrier(0);
      bf16x8 pa2 = *(const bf16x8*)&Pw[prb];
      bf16x8 pa3 = *(const bf16x8*)&Pw[prb + 16];
      __builtin_amdgcn_s_setprio(1);
#pragma unroll
      for (int dt = 0; dt < 3; ++dt) {
        bf16x8 vb2 = *(const bf16x8*)&Vsc[vbase[dt] + (((4 + h5) ^ ve7[dt]) << 3)];
        bf16x8 vb3 = *(const bf16x8*)&Vsc[vbase[dt] + (((6 + h5) ^ ve7[dt]) << 3)];
        accO[dt] = __builtin_amdgcn_mfma_f32_32x32x16_bf16(pa2, vb2, accO[dt], 0, 0, 0);
        accO[dt] = __builtin_amdgcn_mfma_f32_32x32x16_bf16(pa3, vb3, accO[dt], 0, 0, 0);
      }
      __builtin_amdgcn_s_setprio(0);
    }

    short* t1 = Ksc; Ksc = Ksn; Ksn = t1;
    short* t2 = Vsc; Vsc = Vsn; Vsn = t2;
  }

  // ---- split-K combine via LDS (all buffers dead now) ----
  __syncthreads();
  float* comb = (float*)lds;
  const int fbase = (hw * 64 + l) * 48;
  if (grp == 1) {
#pragma unroll
    for (int dt = 0; dt < 3; ++dt)
#pragma unroll
      for (int q4 = 0; q4 < 4; ++q4) {
        f32x4 ch = { accO[dt][q4 * 4], accO[dt][q4 * 4 + 1],
                     accO[dt][q4 * 4 + 2], accO[dt][q4 * 4 + 3] };
        *(f32x4*)&comb[fbase + dt * 16 + q4 * 4] = ch;
      }
  }
  __syncthreads();
  if (grp == 0) {
#pragma unroll
    for (int dt = 0; dt < 3; ++dt)
#pragma unroll
      for (int q4 = 0; q4 < 4; ++q4) {
        f32x4 ch = *(const f32x4*)&comb[fbase + dt * 16 + q4 * 4];
#pragma unroll
        for (int j = 0; j < 4; ++j) accO[dt][q4 * 4 + j] += ch[j];
      }

    // denominator: ones-row output lives at col 72 (dt=2, c31==8)
    float inv[16];
#pragma unroll
    for (int r = 0; r < 16; ++r)
      inv[r] = 1.0f / __shfl(accO[2][r], (l & 32) | 8);

#pragma unroll
    for (int dt = 0; dt < 3; ++dt) {
      int d = dt * 32 + c31;
      if (d < HD_) {
#pragma unroll
        for (int r = 0; r < 16; ++r) {
          int row = rbase + (r & 3) + 8 * (r >> 2);
          O[(size_t)(b * S_ + row) * HID_ + h * HD_ + d] = f2bf(accO[dt][r] * inv[r]);
        }
      }
    }
  }
}

// ---------------- host ----------------
extern "C" void kernel_launch(void* const* d_in, const int* in_sizes, int n_in,
                              void* d_out, int out_size, void* d_ws, size_t ws_size,
                              hipStream_t stream) {
  const float* hs = (const float*)d_in[0];
  // d_in[1] = attention_mask (causal, implemented analytically — unused)
  const float* wq = (const float*)d_in[2];
  const float* wk = (const float*)d_in[3];
  const float* wv = (const float*)d_in[4];
  const float* wo = (const float*)d_in[5];

  char* ws = (char*)d_ws;
  short* Xb  = (short*)(ws + 0);          // 4096x1152 bf16
  short* Qb  = (short*)(ws + 9437184);    // 4096x1152 (pre-RoPE, permuted d)
  short* Kb  = (short*)(ws + 18874368);   // 4096x288  (RoPE'd, permuted d)
  short* Vt  = (short*)(ws + 23592960);   // 8x80x2048 (transposed V + ones row)
  short* Ob  = (short*)(ws + 26214400);   // 4096x1152
  short* wqb = (short*)(ws + 35651584);   // 1152x1152 (row-permuted)
  short* wkb = (short*)(ws + 38305792);   // 288x1152  (row-permuted)
  short* wvb = (short*)(ws + 38969344);   // 288x1152
  short* wob = (short*)(ws + 39632896);   // 1152x1152
  float2* tab = (float2*)(ws + 42287104); // 2048x36 cos/sin

  // fused convert (wq/wk row-permuted) + RoPE table + Vt ones-rows
  k_cvt_all<<<2048, 256, 0, stream>>>(
      (const float4*)hs, (const float4*)wq, (const float4*)wk, (const float4*)wv,
      (const float4*)wo,
      (s4v*)Xb, (s4v*)wqb, (s4v*)wkb, (s4v*)wvb, (s4v*)wob, tab, Vt,
      MTOT * HID_ / 4, HID_ * HID_ / 4, KVDIM * HID_ / 4, KVDIM * HID_ / 4,
      HID_ * HID_ / 4);

  // fused QKV projection + K-RoPE + V-transpose epilogue (N = 1728)
  k_gemm_qkv<<<dim3(32, 14), 256, 0, stream>>>(Xb, wqb, wkb, wvb, Qb, Kb, Vt, tab);

  // flash attention (32x32 MFMA, 2 kt-split groups x 4 heads)
  k_flash<<<512, 512, 0, stream>>>(Qb, Kb, Vt, Ob, tab);

  k_gemm_o<<<dim3(32, 9), 256, 0, stream>>>(Ob, wob, (float*)d_out, MTOT, HID_, HID_);
}

// Round 20
// 108.393 us; speedup vs baseline: 1.1380x; 1.1380x over previous
//
#include <hip/hip_runtime.h>
#include <hip/hip_bf16.h>
#include <cstddef>

#define B_   2
#define S_   2048
#define HID_ 1152
#define NH_  16
#define NKV_ 4
#define HD_  72
#define MTOT (B_ * S_)   // 4096
#define KVDIM (NKV_ * HD_)  // 288

typedef float f32x4 __attribute__((ext_vector_type(4)));
typedef short bf16x8 __attribute__((ext_vector_type(8)));
typedef short s4v __attribute__((ext_vector_type(4)));

__device__ __forceinline__ float bf2f(short x) {
  unsigned int u = ((unsigned int)(unsigned short)x) << 16;
  return __builtin_bit_cast(float, u);
}
__device__ __forceinline__ short f2bf(float f) {
  unsigned int u = __builtin_bit_cast(unsigned int, f);
  u += 0x7fff + ((u >> 16) & 1);   // RNE
  return (short)(u >> 16);
}

// hardware v_exp_f32 (2^x) — exp2f() without -ffast-math lowers to ~25 VALU ops.
__device__ __forceinline__ float fast_exp2(float x) {
#if __has_builtin(__builtin_amdgcn_exp2f)
  return __builtin_amdgcn_exp2f(x);
#else
  return exp2f(x);
#endif
}

__device__ __forceinline__ void async16(const short* g, short* lds) {
  __builtin_amdgcn_global_load_lds((const __attribute__((address_space(1))) void*)g,
                                   (__attribute__((address_space(3))) void*)lds,
                                   16, 0, 0);
}

// ------- fused fp32->bf16 convert + RoPE table + Vt ones-rows, 1 launch -------
// wq/wk rows PERMUTED on write (pair (i, i+36) -> adjacent (2i, 2i+1)), making
// RoPE pairs adjacent in the projected Q/K feature dim (QK^T invariant under a
// common d-permutation). Q-RoPE then happens in-register at flash Q-load;
// K-RoPE in the QKV-GEMM epilogue. Also writes Vt rows d=72..79 (72 = 1.0 for
// the free softmax denominator, 73..79 = 0).
__global__ void k_cvt_all(const float4* __restrict__ s0, const float4* __restrict__ s1,
                          const float4* __restrict__ s2, const float4* __restrict__ s3,
                          const float4* __restrict__ s4,
                          s4v* __restrict__ d0, s4v* __restrict__ d1, s4v* __restrict__ d2,
                          s4v* __restrict__ d3, s4v* __restrict__ d4,
                          float2* __restrict__ tab, short* __restrict__ Vt,
                          int n0, int n1, int n2, int n3, int n4t) {
  int ncvt = n0 + n1 + n2 + n3 + n4t;
  int ntab = S_ * 36;
  int total = ncvt + ntab + 32768;
  for (int i = blockIdx.x * blockDim.x + threadIdx.x; i < total;
       i += gridDim.x * blockDim.x) {
    if (i < ncvt) {
      const float4* s;
      s4v* d;
      int off = i;
      bool perm = false;
      if (off < n0) { s = s0; d = d0; }
      else {
        off -= n0;
        if (off < n1) { s = s1; d = d1; perm = true; }       // wq
        else {
          off -= n1;
          if (off < n2) { s = s2; d = d2; perm = true; }     // wk
          else {
            off -= n2;
            if (off < n3) { s = s3; d = d3; }
            else { off -= n3; s = s4; d = d4; }
          }
        }
      }
      float4 v = s[off];
      s4v o = { f2bf(v.x), f2bf(v.y), f2bf(v.z), f2bf(v.w) };
      int out = off;
      if (perm) {
        int r = off / 288, k4 = off - r * 288;   // 288 float4 per 1152-col row
        int hh = r / 72, ii = r - hh * 72;
        int pr = hh * 72 + (ii < 36 ? 2 * ii : 2 * (ii - 36) + 1);
        out = pr * 288 + k4;
      }
      d[out] = o;
    } else if (i < ncvt + ntab) {
      int idx = i - ncvt;
      int ii = idx % 36, s = idx / 36;
      float freq = powf(10000.0f, -(float)ii / 36.0f);
      float a = (float)s * freq;
      tab[idx] = make_float2(cosf(a), sinf(a));
    } else {
      int idx2 = i - ncvt - ntab;        // 0..32767, s4v units
      int t = idx2 << 2;
      int sp = t & 2047;
      int rest = t >> 11;                // 0..63
      int dr = rest & 7;                 // row - 72
      int bkv = rest >> 3;
      s4v val = {};
      if (dr == 0) { val[0] = (short)0x3F80; val[1] = (short)0x3F80;
                     val[2] = (short)0x3F80; val[3] = (short)0x3F80; }
      *(s4v*)(Vt + (size_t)bkv * 163840 + (size_t)(72 + dr) * 2048 + sp) = val;
    }
  }
}

// ---------------- GEMM geometry: 128x128x4-wave, LDS DOUBLE-BUFFERED --------
#define BM 128
#define BN 128
#define BK 32

// Fused QKV projection: C = X @ [wq;wk;wv]^T over N=1728, one launch.
__global__ __launch_bounds__(256) void k_gemm_qkv(const short* __restrict__ A,
                                                  const short* __restrict__ Wq,
                                                  const short* __restrict__ Wk,
                                                  const short* __restrict__ Wv,
                                                  short* __restrict__ Qo,
                                                  short* __restrict__ Ko,
                                                  short* __restrict__ Vt,
                                                  const float2* __restrict__ tab) {
  const int K = HID_, NTOT = 1728;
  __shared__ short smem[16384];           // 2x (As 4096 + Bs 4096) shorts
  short* As0 = smem;
  short* Bs0 = smem + 4096;
  short* As1 = smem + 8192;
  short* Bs1 = smem + 12288;
  const int tid = threadIdx.x;
  const int l = tid & 63;
  const int w = tid >> 6;
  const int bm = blockIdx.x * BM;
  const int bn = blockIdx.y * BN;
  const int wr = (w >> 1) * 64;
  const int wc = (w & 1) * 64;
  const int c15 = l & 15, g = l >> 4;
  const int r0 = tid >> 2;
  const int c0 = (tid & 3) * 8;

  const short* srcA[2];
  const short* srcB[2];
#pragma unroll
  for (int it = 0; it < 2; ++it) {
    int ar = bm + it * 64 + r0;
    int br = bn + it * 64 + r0;
    if (br > NTOT - 1) br = NTOT - 1;
    const short* bsrc;
    if (br < 1152)      bsrc = Wq + (size_t)br * K;
    else if (br < 1440) bsrc = Wk + (size_t)(br - 1152) * K;
    else                bsrc = Wv + (size_t)(br - 1440) * K;
    srcA[it] = A + (size_t)ar * K + c0;
    srcB[it] = bsrc + c0;
  }

  auto STAGE = [&](short* Ad, short* Bd) {
#pragma unroll
    for (int it = 0; it < 2; ++it) {
      async16(srcA[it], &Ad[(it * 64 + r0) * BK + c0]);
      async16(srcB[it], &Bd[(it * 64 + r0) * BK + c0]);
      srcA[it] += BK;
      srcB[it] += BK;
    }
  };

  f32x4 acc[4][4] = {};

  STAGE(As0, Bs0);
  short *Ac = As0, *Bc = Bs0, *An = As1, *Bn = Bs1;

  for (int k0 = 0; k0 < K; k0 += BK) {
    asm volatile("s_waitcnt vmcnt(0)" ::: "memory");
    __builtin_amdgcn_sched_barrier(0);
    __syncthreads();
    if (k0 + BK < K) STAGE(An, Bn);

    bf16x8 af[4], bfr[4];
#pragma unroll
    for (int t = 0; t < 4; ++t) {
      af[t]  = *(const bf16x8*)&Ac[(wr + t * 16 + c15) * BK + g * 8];
      bfr[t] = *(const bf16x8*)&Bc[(wc + t * 16 + c15) * BK + g * 8];
    }
#pragma unroll
    for (int mt = 0; mt < 4; ++mt)
#pragma unroll
      for (int nt = 0; nt < 4; ++nt)
        acc[mt][nt] = __builtin_amdgcn_mfma_f32_16x16x32_bf16(af[mt], bfr[nt], acc[mt][nt], 0, 0, 0);

    short* t1 = Ac; Ac = An; An = t1;
    short* t2 = Bc; Bc = Bn; Bn = t2;
  }

#pragma unroll
  for (int mt = 0; mt < 4; ++mt)
#pragma unroll
    for (int nt = 0; nt < 4; ++nt) {
      int col = bn + wc + nt * 16 + c15;       // range is wave-uniform per nt
      if (col < 1152) {
#pragma unroll
        for (int j = 0; j < 4; ++j) {
          int row = bm + wr + mt * 16 + g * 4 + j;
          Qo[(size_t)row * HID_ + col] = f2bf(acc[mt][nt][j]);
        }
      } else if (col < 1440) {
        int ch = col - 1152;
        int ii = (ch % 72) >> 1;               // pairs adjacent (permuted wk)
#pragma unroll
        for (int j = 0; j < 4; ++j) {
          int row = bm + wr + mt * 16 + g * 4 + j;
          float v = acc[mt][nt][j];
          float p = __shfl_xor(v, 1);
          float2 cs = tab[(size_t)(row & (S_ - 1)) * 36 + ii];
          float r = (c15 & 1) ? (v * cs.x + p * cs.y)
                              : (v * cs.x - p * cs.y);
          Ko[(size_t)row * KVDIM + ch] = f2bf(r);
        }
      } else if (col < NTOT) {
        int cv = col - 1440;
        int d = cv % 72, kvh = cv / 72;
        int row0 = bm + wr + mt * 16 + g * 4;
        int bkv = (row0 >> 11) * 4 + kvh;
        s4v out;
#pragma unroll
        for (int j = 0; j < 4; ++j) out[j] = f2bf(acc[mt][nt][j]);
        *(s4v*)(Vt + (size_t)bkv * 163840 + (size_t)d * 2048 + (row0 & 2047)) = out;
      }
    }
}

// Output projection: C[M,N] = A[M,K] * B[N,K]^T, fp32 out (double-buffered)
__global__ __launch_bounds__(256) void k_gemm_o(const short* __restrict__ A,
                                                const short* __restrict__ Bm,
                                                float* __restrict__ C,
                                                int M, int N, int K) {
  __shared__ short smem[16384];
  short* As0 = smem;
  short* Bs0 = smem + 4096;
  short* As1 = smem + 8192;
  short* Bs1 = smem + 12288;
  const int tid = threadIdx.x;
  const int l = tid & 63;
  const int w = tid >> 6;
  const int bm = blockIdx.x * BM;
  const int bn = blockIdx.y * BN;
  const int wr = (w >> 1) * 64;
  const int wc = (w & 1) * 64;
  const int c15 = l & 15, g = l >> 4;
  const int r0 = tid >> 2;
  const int c0 = (tid & 3) * 8;

  const short* srcA[2];
  const short* srcB[2];
#pragma unroll
  for (int it = 0; it < 2; ++it) {
    int ar = bm + it * 64 + r0;
    int br = bn + it * 64 + r0;
    if (br > N - 1) br = N - 1;
    srcA[it] = A + (size_t)ar * K + c0;
    srcB[it] = Bm + (size_t)br * K + c0;
  }

  auto STAGE = [&](short* Ad, short* Bd) {
#pragma unroll
    for (int it = 0; it < 2; ++it) {
      async16(srcA[it], &Ad[(it * 64 + r0) * BK + c0]);
      async16(srcB[it], &Bd[(it * 64 + r0) * BK + c0]);
      srcA[it] += BK;
      srcB[it] += BK;
    }
  };

  f32x4 acc[4][4] = {};

  STAGE(As0, Bs0);
  short *Ac = As0, *Bc = Bs0, *An = As1, *Bn = Bs1;

  for (int k0 = 0; k0 < K; k0 += BK) {
    asm volatile("s_waitcnt vmcnt(0)" ::: "memory");
    __builtin_amdgcn_sched_barrier(0);
    __syncthreads();
    if (k0 + BK < K) STAGE(An, Bn);

    bf16x8 af[4], bfr[4];
#pragma unroll
    for (int t = 0; t < 4; ++t) {
      af[t]  = *(const bf16x8*)&Ac[(wr + t * 16 + c15) * BK + g * 8];
      bfr[t] = *(const bf16x8*)&Bc[(wc + t * 16 + c15) * BK + g * 8];
    }
#pragma unroll
    for (int mt = 0; mt < 4; ++mt)
#pragma unroll
      for (int nt = 0; nt < 4; ++nt)
        acc[mt][nt] = __builtin_amdgcn_mfma_f32_16x16x32_bf16(af[mt], bfr[nt], acc[mt][nt], 0, 0, 0);

    short* t1 = Ac; Ac = An; An = t1;
    short* t2 = Bc; Bc = Bn; Bn = t2;
  }

#pragma unroll
  for (int mt = 0; mt < 4; ++mt)
#pragma unroll
    for (int nt = 0; nt < 4; ++nt)
#pragma unroll
      for (int j = 0; j < 4; ++j) {
        int row = bm + wr + mt * 16 + g * 4 + j;
        int col = bn + wc + nt * 16 + c15;
        if (col < N) C[(size_t)row * N + col] = acc[mt][nt][j];
      }
}

// ---------------- Flash attention: 8 waves = 2 qt-tiles x 4 heads -----------
// R18 structure + PV interleave: PV(ks2=0,1) issued right after P-phase-A read
// so phase-B's write + fence latency hides under 10 MFMAs. Everything else
// identical to R18 (best known: KT=128, shared dbuf staging, balanced qt
// pairing, Q-RoPE at load, fixed-shift softmax, ones-row denominator).
#define QB 16
#define KT 128

__global__ __launch_bounds__(512, 2) void k_flash(const short* __restrict__ Q,
                                                  const short* __restrict__ Kg,
                                                  const short* __restrict__ Vt,
                                                  short* __restrict__ O,
                                                  const float2* __restrict__ tab) {
  const int bid = blockIdx.x;
  const int bkv = bid & 7;            // one (b,kv) per XCD -> K/V L2-resident
  const int sidx = bid >> 3;          // 0..63
  const int qtp = (bid < 256) ? sidx : 95 - sidx;   // balanced CU pairing
  const int b = bkv >> 2, kv = bkv & 3;
  const int tid = threadIdx.x;
  const int w = tid >> 6, l = tid & 63;
  const int grp = w >> 2, hw = w & 3;
  const int h = kv * 4 + hw;
  const int qt = 127 - 2 * qtp - grp; // grp0 = hi tile, grp1 = hi-1
  const int q0 = qt * QB;
  const int c15 = l & 15, g = l >> 4;

  // 77824 B -> 2 blocks/CU, 16 waves/CU. Ks[128][72] + Vs[80][128], x2.
  __shared__ short lds[38912];
  short* Ks0 = lds;
  short* Vs0 = lds + 9216;
  short* Ks1 = lds + 19456;
  short* Vs1 = lds + 28672;

  const float SCL = 0.117851130f * 1.4426950408889634f;  // 1/sqrt(72)*log2(e)
  const float SHIFT = 8.0f;  // fixed exponent shift (cancels in final divide)

  const short* Qbase = Q + (size_t)(b * S_) * HID_ + h * HD_;
  const short* Kbase = Kg + (size_t)(b * S_) * KVDIM + kv * HD_;
  const short* Vbase = Vt + (size_t)bkv * 80 * S_;

  // LDS lane offsets (shorts)
  const int lane_k = c15 * 72 + g * 8;            // K frag base; +ct*1152+ks*32
  int lane_v[4];
#pragma unroll
  for (int ks2 = 0; ks2 < 4; ++ks2)
    lane_v[ks2] = c15 * 128 + (((ks2 * 4 + g) ^ c15) << 3);   // +dt*2048
  const int pbase = w * 1152;                     // P region inside dead Ksc
  const int pw_off = pbase + (g * 4) * 72 + c15;  // +j*72 + ct*16 (64-col phase)
  const int pr_off = pbase + c15 * 72 + g * 8;    // +ks2*32

  // Q fragments: load + in-register RoPE (pairs adjacent) + pre-scale
  bf16x8 qf[3];
  const bf16x8 zfrag = {0, 0, 0, 0, 0, 0, 0, 0};
  {
    int row = q0 + c15;
    const short* qrow = Qbase + (size_t)row * HID_;
    const float2* trow = tab + (size_t)row * 36;
#pragma unroll
    for (int ks = 0; ks < 3; ++ks) {
      int d0 = ks * 32 + g * 8;
      if (d0 < HD_) {
        bf16x8 raw = *(const bf16x8*)(qrow + d0);
        bf16x8 o;
#pragma unroll
        for (int e = 0; e < 8; e += 2) {
          float2 cs = trow[(d0 + e) >> 1];
          float x1 = bf2f(raw[e]), x2 = bf2f(raw[e + 1]);
          o[e]     = f2bf((x1 * cs.x - x2 * cs.y) * SCL);
          o[e + 1] = f2bf((x2 * cs.x + x1 * cs.y) * SCL);
        }
        qf[ks] = o;
      } else {
        qf[ks] = zfrag;
      }
    }
  }

  f32x4 accO[5] = {};

  const int nkt   = (16 * qt + 143) >> 7;              // this wave's tiles
  const int nkt_m = (16 * (127 - 2 * qtp) + 143) >> 7; // block max (grp0)
  const int nfull = (16 * qt + 1) >> 7;                // unmasked tiles

  // cooperative stage (512 thr): K = 1152 chunks, V rows 0..72 = 1168 chunks
  auto STAGE = [&](int kb, short* Kd, short* Vd) {
    const short* kp = Kbase + (size_t)kb * KVDIM;
    const short* vp = Vbase + kb;
#pragma unroll
    for (int i = 0; i < 5; ++i) {
      int c = tid + 512 * i;
      if (c < 1152) {
        int row = c / 9, cc = c - row * 9;
        async16(kp + (size_t)row * KVDIM + cc * 8, &Kd[c * 8]);
      } else if (c < 2320) {
        int c2 = c - 1152;
        int row = c2 >> 4, slot = c2 & 15;
        async16(vp + (size_t)row * S_ + ((slot ^ (row & 15)) << 3), &Vd[c2 * 8]);
      }
    }
  };

  STAGE(0, Ks0, Vs0);
  short *Ksc = Ks0, *Vsc = Vs0, *Ksn = Ks1, *Vsn = Vs1;

  for (int kt = 0; kt < nkt_m; ++kt) {
    const bool act = kt < nkt;
    // own share of STAGE(kt) drained, then block-wide visibility
    asm volatile("s_waitcnt vmcnt(0)" ::: "memory");
    __builtin_amdgcn_sched_barrier(0);
    __syncthreads();
    if (kt + 1 < nkt_m) STAGE((kt + 1) * KT, Ksn, Vsn);

    f32x4 sc[8] = {};
    if (act) {
      const int kbase = kt * KT;
      // ---- QK^T over 8 ct sub-tiles ----
      __builtin_amdgcn_s_setprio(1);
#pragma unroll
      for (int ct = 0; ct < 8; ++ct)
#pragma unroll
        for (int ks = 0; ks < 3; ++ks) {
          bf16x8 kf = *(const bf16x8*)&Ksc[lane_k + ct * 1152 + ks * 32];
          sc[ct] = __builtin_amdgcn_mfma_f32_16x16x32_bf16(qf[ks], kf, sc[ct], 0, 0, 0);
        }
      __builtin_amdgcn_s_setprio(0);

      // ---- mask + fixed-shift exp2 (hw v_exp_f32, no max, no reduce) ----
      const int qrow = q0 + g * 4;  // + j
      if (kt >= nfull) {
#pragma unroll
        for (int ct = 0; ct < 8; ++ct) {
          int col = kbase + ct * 16 + c15;
#pragma unroll
          for (int j = 0; j < 4; ++j)
            if (col > qrow + j) sc[ct][j] = -1e30f;
        }
      }
#pragma unroll
      for (int ct = 0; ct < 8; ++ct)
#pragma unroll
        for (int j = 0; j < 4; ++j)
          sc[ct][j] = fast_exp2(sc[ct][j] - SHIFT);
    }

    // ---- all 8 waves done reading Ksc -> safe to overwrite with P ----
    __syncthreads();
    if (act) {
      // phase A: P cols 0..63
#pragma unroll
      for (int ct = 0; ct < 4; ++ct)
#pragma unroll
        for (int j = 0; j < 4; ++j)
          Ksc[pw_off + j * 72 + ct * 16] = f2bf(sc[ct][j]);
      asm volatile("s_waitcnt lgkmcnt(0)" ::: "memory");
      __builtin_amdgcn_sched_barrier(0);
      bf16x8 pa0 = *(const bf16x8*)&Ksc[pr_off];
      bf16x8 pa1 = *(const bf16x8*)&Ksc[pr_off + 32];
      asm volatile("s_waitcnt lgkmcnt(0)" ::: "memory");
      __builtin_amdgcn_sched_barrier(0);
      // PV over k 0..63 NOW — phase-B write + fence latency hides under MFMA
      __builtin_amdgcn_s_setprio(1);
#pragma unroll
      for (int dt = 0; dt < 5; ++dt) {
        bf16x8 vb0 = *(const bf16x8*)&Vsc[lane_v[0] + dt * 2048];
        bf16x8 vb1 = *(const bf16x8*)&Vsc[lane_v[1] + dt * 2048];
        accO[dt] = __builtin_amdgcn_mfma_f32_16x16x32_bf16(pa0, vb0, accO[dt], 0, 0, 0);
        accO[dt] = __builtin_amdgcn_mfma_f32_16x16x32_bf16(pa1, vb1, accO[dt], 0, 0, 0);
      }
      __builtin_amdgcn_s_setprio(0);
      // phase B: P cols 64..127 (same per-wave region, prior reads retired)
#pragma unroll
      for (int ct = 0; ct < 4; ++ct)
#pragma unroll
        for (int j = 0; j < 4; ++j)
          Ksc[pw_off + j * 72 + ct * 16] = f2bf(sc[4 + ct][j]);
      asm volatile("s_waitcnt lgkmcnt(0)" ::: "memory");
      __builtin_amdgcn_sched_barrier(0);
      bf16x8 pa2 = *(const bf16x8*)&Ksc[pr_off];
      bf16x8 pa3 = *(const bf16x8*)&Ksc[pr_off + 32];

      // ---- PV over k 64..127 ----
      __builtin_amdgcn_s_setprio(1);
#pragma unroll
      for (int dt = 0; dt < 5; ++dt) {
        bf16x8 vb2 = *(const bf16x8*)&Vsc[lane_v[2] + dt * 2048];
        bf16x8 vb3 = *(const bf16x8*)&Vsc[lane_v[3] + dt * 2048];
        accO[dt] = __builtin_amdgcn_mfma_f32_16x16x32_bf16(pa2, vb2, accO[dt], 0, 0, 0);
        accO[dt] = __builtin_amdgcn_mfma_f32_16x16x32_bf16(pa3, vb3, accO[dt], 0, 0, 0);
      }
      __builtin_amdgcn_s_setprio(0);
    }

    short* t1 = Ksc; Ksc = Ksn; Ksn = t1;
    short* t2 = Vsc; Vsc = Vsn; Vsn = t2;
  }

  // ---- epilogue: denominator from ones-row (accO[4] @ c15==8), then write ----
  float lj[4];
#pragma unroll
  for (int j = 0; j < 4; ++j)
    lj[j] = 1.0f / __shfl(accO[4][j], (l & 48) | 8);
#pragma unroll
  for (int dt = 0; dt < 5; ++dt) {
    int d = dt * 16 + c15;
    if (d < HD_) {
#pragma unroll
      for (int j = 0; j < 4; ++j) {
        int row = q0 + g * 4 + j;
        O[(size_t)(b * S_ + row) * HID_ + h * HD_ + d] = f2bf(accO[dt][j] * lj[j]);
      }
    }
  }
}

// ---------------- host ----------------
extern "C" void kernel_launch(void* const* d_in, const int* in_sizes, int n_in,
                              void* d_out, int out_size, void* d_ws, size_t ws_size,
                              hipStream_t stream) {
  const float* hs = (const float*)d_in[0];
  // d_in[1] = attention_mask (causal, implemented analytically — unused)
  const float* wq = (const float*)d_in[2];
  const float* wk = (const float*)d_in[3];
  const float* wv = (const float*)d_in[4];
  const float* wo = (const float*)d_in[5];

  char* ws = (char*)d_ws;
  short* Xb  = (short*)(ws + 0);          // 4096x1152 bf16
  short* Qb  = (short*)(ws + 9437184);    // 4096x1152 (pre-RoPE, permuted d)
  short* Kb  = (short*)(ws + 18874368);   // 4096x288  (RoPE'd, permuted d)
  short* Vt  = (short*)(ws + 23592960);   // 8x80x2048 (transposed V + ones row)
  short* Ob  = (short*)(ws + 26214400);   // 4096x1152
  short* wqb = (short*)(ws + 35651584);   // 1152x1152 (row-permuted)
  short* wkb = (short*)(ws + 38305792);   // 288x1152  (row-permuted)
  short* wvb = (short*)(ws + 38969344);   // 288x1152
  short* wob = (short*)(ws + 39632896);   // 1152x1152
  float2* tab = (float2*)(ws + 42287104); // 2048x36 cos/sin

  // fused convert (wq/wk row-permuted) + RoPE table + Vt ones-rows
  k_cvt_all<<<2048, 256, 0, stream>>>(
      (const float4*)hs, (const float4*)wq, (const float4*)wk, (const float4*)wv,
      (const float4*)wo,
      (s4v*)Xb, (s4v*)wqb, (s4v*)wkb, (s4v*)wvb, (s4v*)wob, tab, Vt,
      MTOT * HID_ / 4, HID_ * HID_ / 4, KVDIM * HID_ / 4, KVDIM * HID_ / 4,
      HID_ * HID_ / 4);

  // fused QKV projection + K-RoPE + V-transpose epilogue (N = 1728)
  k_gemm_qkv<<<dim3(32, 14), 256, 0, stream>>>(Xb, wqb, wkb, wvb, Qb, Kb, Vt, tab);

  // flash attention (8 waves: 2 qt-tiles x 4 heads share K/V staging)
  k_flash<<<512, 512, 0, stream>>>(Qb, Kb, Vt, Ob, tab);

  k_gemm_o<<<dim3(32, 9), 256, 0, stream>>>(Ob, wob, (float*)d_out, MTOT, HID_, HID_);
}